// Round 2
// baseline (11691.743 us; speedup 1.0000x reference)
//
#include <hip/hip_runtime.h>
#include <hip/hip_bf16.h>
#include <cstdint>
#include <cstddef>

// Problem: V=50000 T=32 E=256 H=512 B=64 S=512
// Combined recurrence GEMM K = E + H = 768, gates = 4H = 2048 per dir.

typedef __attribute__((ext_vector_type(8))) short short8;
typedef __attribute__((ext_vector_type(4))) float f32x4;

__device__ __forceinline__ unsigned short f2b(float x){
  unsigned u = __float_as_uint(x);
  unsigned r = u + 0x7FFFu + ((u >> 16) & 1u);   // RNE
  return (unsigned short)(r >> 16);
}
__device__ __forceinline__ float b2f(unsigned short b){
  return __uint_as_float(((unsigned)b) << 16);
}
__device__ __forceinline__ float sigf(float x){
  return 1.f / (1.f + __expf(-x));
}
__device__ __forceinline__ float tanhfast(float x){
  return 1.f - 2.f / (__expf(2.f * x) + 1.f);
}

// ---------------- prep kernels ----------------

// Wc (2048 x 768) bf16 : rows are gate-major (g*512 + j), cols = [w_ih | w_hh]
__global__ void prep_wc_kernel(const float* __restrict__ w_ih, const float* __restrict__ w_hh,
                               unsigned short* __restrict__ wc){
  int idx = blockIdx.x * 256 + threadIdx.x;
  if(idx >= 2048 * 768) return;
  int g = idx / 768, k = idx - g * 768;
  float v = (k < 256) ? w_ih[g * 256 + k] : w_hh[g * 512 + (k - 256)];
  wc[idx] = f2b(v);
}

// fcwN [n][k] (32 x 1024) bf16 — direct convert of fc_w
__global__ void prep_fcw_kernel(const float* __restrict__ fc_w, unsigned short* __restrict__ fcwN){
  int idx = blockIdx.x * 256 + threadIdx.x;   // 32768
  fcwN[idx] = f2b(fc_w[idx]);
}

// gather embeddings -> bf16 (S, B, E)
__global__ void gather_kernel(const float* __restrict__ emb, const int* __restrict__ x,
                              unsigned short* __restrict__ e_bf){
  int tok = blockIdx.x;            // s*64 + b
  int s = tok >> 6, b = tok & 63;
  int row = x[b * 512 + s];
  int k = threadIdx.x;
  e_bf[(size_t)tok * 256 + k] = f2b(emb[(size_t)row * 256 + k]);
}

// zero the step-completion flags: [2][64] padded to 16B each
__global__ void init_flags_kernel(unsigned int* __restrict__ flags){
  int idx = blockIdx.x * 256 + threadIdx.x;    // 512 uints
  if(idx < 2 * 64 * 4) flags[idx] = 0;
}

// ---------------- persistent bidirectional LSTM ----------------
// grid = 128 WGs x 256 threads. dir = wg>>6, slice = wg&63 (8 h-dims).
// WG output per step: 64 batch x 32 gate-cols (cols = g*8 + jj, g=0..3 gates, jj=0..7 dims).
// wave w = M-tile (batch rows 16w..16w+15), covers both 16-col n-tiles.
// Weights: 48 x short8 = 192 VGPR per lane, loaded once. c-state in registers.
// Sync: per-dir flag array; producer of step t sets flag=t+1 (release, agent);
// consumer at step t polls all 64 flags >= t (acquire, agent).
__global__ __launch_bounds__(256, 1) void lstm_persist(
    const unsigned short* __restrict__ e_bf,
    const unsigned short* __restrict__ Wc_f, const unsigned short* __restrict__ Wc_b,
    const float* __restrict__ b_f, const float* __restrict__ b_b,
    unsigned short* __restrict__ st_f, unsigned short* __restrict__ st_b,
    unsigned int* __restrict__ flags)
{
  __shared__ float gate_lds[64 * 33];   // 64 b x 32 cols, pad 33

  const int tid  = threadIdx.x;
  const int wid  = tid >> 6;
  const int lane = tid & 63;
  const int wg   = blockIdx.x;
  const int dir  = wg >> 6;
  const int slice= wg & 63;
  const int j0   = slice * 8;

  const unsigned short* Wc   = dir ? Wc_b : Wc_f;
  const float*          bias = dir ? b_b  : b_f;
  unsigned short*       st   = dir ? st_b : st_f;
  unsigned int* myflag = flags + (size_t)(dir * 64 + slice) * 4;
  const unsigned int* dflags = flags + (size_t)dir * 64 * 4;

  const int r0 = lane & 15;
  const int kb = (lane >> 4) * 8;

  // --- load static B fragments: col c = nt*16 + r0 ; W row = (c>>3)*512 + j0 + (c&7)
  short8 bfrag[2][24];
#pragma unroll
  for(int nt = 0; nt < 2; nt++){
    int c = nt * 16 + r0;
    const unsigned short* wrow = Wc + (size_t)((c >> 3) * 512 + j0 + (c & 7)) * 768;
#pragma unroll
    for(int kc = 0; kc < 24; kc++)
      bfrag[nt][kc] = *(const short8*)(wrow + kc * 32 + kb);
  }

  // --- epilogue thread mapping: thread owns (b2, jj) x {b2, b2+32}
  const int ejj = tid & 7;
  const int eb2 = tid >> 3;          // 0..31
  const float bi = bias[0 * 512 + j0 + ejj];
  const float bff= bias[1 * 512 + j0 + ejj];
  const float bg = bias[2 * 512 + j0 + ejj];
  const float bo = bias[3 * 512 + j0 + ejj];
  float c0 = 0.f, c1 = 0.f;

  const int arow = wid * 16 + r0;    // batch row for A fragments

  for(int t = 0; t < 512; t++){
    const int t_e = dir ? (511 - t) : t;

    // issue e-part A fragment loads (independent of h)
    const unsigned short* ep = e_bf + (size_t)t_e * 16384 + (size_t)arow * 256;
    short8 ef[8];
#pragma unroll
    for(int kc = 0; kc < 8; kc++)
      ef[kc] = *(const short8*)(ep + kc * 32 + kb);

    // wait for previous step's h (all 64 producer WGs of this dir)
    if(t > 0){
      int ok;
      do{
        unsigned fv = __hip_atomic_load(dflags + ((tid & 63) << 2),
                                        __ATOMIC_ACQUIRE, __HIP_MEMORY_SCOPE_AGENT);
        ok = __syncthreads_and((int)(fv >= (unsigned)t));
        if(!ok) __builtin_amdgcn_s_sleep(2);
      }while(!ok);
    }

    f32x4 aA0 = {0,0,0,0}, aA1 = {0,0,0,0};   // nt0 even/odd chains
    f32x4 aB0 = {0,0,0,0}, aB1 = {0,0,0,0};   // nt1 even/odd chains

    if(t > 0){
      const unsigned short* hp = st + (size_t)(t - 1) * 32768 + (size_t)arow * 512;
      short8 hf[16];
#pragma unroll
      for(int kc = 0; kc < 16; kc++)
        hf[kc] = *(const short8*)(hp + kc * 32 + kb);

      // e-part MFMAs (overlap with h loads in flight)
#pragma unroll
      for(int kc = 0; kc < 8; kc += 2){
        aA0 = __builtin_amdgcn_mfma_f32_16x16x32_bf16(ef[kc],   bfrag[0][kc],   aA0, 0,0,0);
        aB0 = __builtin_amdgcn_mfma_f32_16x16x32_bf16(ef[kc],   bfrag[1][kc],   aB0, 0,0,0);
        aA1 = __builtin_amdgcn_mfma_f32_16x16x32_bf16(ef[kc+1], bfrag[0][kc+1], aA1, 0,0,0);
        aB1 = __builtin_amdgcn_mfma_f32_16x16x32_bf16(ef[kc+1], bfrag[1][kc+1], aB1, 0,0,0);
      }
#pragma unroll
      for(int kc = 0; kc < 16; kc += 2){
        aA0 = __builtin_amdgcn_mfma_f32_16x16x32_bf16(hf[kc],   bfrag[0][8+kc],   aA0, 0,0,0);
        aB0 = __builtin_amdgcn_mfma_f32_16x16x32_bf16(hf[kc],   bfrag[1][8+kc],   aB0, 0,0,0);
        aA1 = __builtin_amdgcn_mfma_f32_16x16x32_bf16(hf[kc+1], bfrag[0][9+kc],   aA1, 0,0,0);
        aB1 = __builtin_amdgcn_mfma_f32_16x16x32_bf16(hf[kc+1], bfrag[1][9+kc],   aB1, 0,0,0);
      }
    } else {
      // t == 0: h0 = 0, only e-part contributes
#pragma unroll
      for(int kc = 0; kc < 8; kc += 2){
        aA0 = __builtin_amdgcn_mfma_f32_16x16x32_bf16(ef[kc],   bfrag[0][kc],   aA0, 0,0,0);
        aB0 = __builtin_amdgcn_mfma_f32_16x16x32_bf16(ef[kc],   bfrag[1][kc],   aB0, 0,0,0);
        aA1 = __builtin_amdgcn_mfma_f32_16x16x32_bf16(ef[kc+1], bfrag[0][kc+1], aA1, 0,0,0);
        aB1 = __builtin_amdgcn_mfma_f32_16x16x32_bf16(ef[kc+1], bfrag[1][kc+1], aB1, 0,0,0);
      }
    }

    f32x4 g0 = aA0 + aA1;   // cols 0..15  (gates i,f for dims jj=0..7)
    f32x4 g1 = aB0 + aB1;   // cols 16..31 (gates g,o)

    // gates -> LDS (C layout: row = (lane>>4)*4 + r within M-tile, col = nt*16 + r0)
#pragma unroll
    for(int r = 0; r < 4; r++){
      int b = wid * 16 + (lane >> 4) * 4 + r;
      gate_lds[b * 33 + r0]      = g0[r];
      gate_lds[b * 33 + 16 + r0] = g1[r];
    }
    __syncthreads();

    // c/h update: thread handles (b2, jj) and (b2+32, jj)
    {
      int b = eb2;
      float gi = gate_lds[b * 33 + 0  + ejj] + bi;
      float gf = gate_lds[b * 33 + 8  + ejj] + bff;
      float gg = gate_lds[b * 33 + 16 + ejj] + bg;
      float go = gate_lds[b * 33 + 24 + ejj] + bo;
      c0 = sigf(gf) * c0 + sigf(gi) * tanhfast(gg);
      st[(size_t)t * 32768 + (size_t)b * 512 + j0 + ejj] = f2b(sigf(go) * tanhfast(c0));
    }
    {
      int b = 32 + eb2;
      float gi = gate_lds[b * 33 + 0  + ejj] + bi;
      float gf = gate_lds[b * 33 + 8  + ejj] + bff;
      float gg = gate_lds[b * 33 + 16 + ejj] + bg;
      float go = gate_lds[b * 33 + 24 + ejj] + bo;
      c1 = sigf(gf) * c1 + sigf(gi) * tanhfast(gg);
      st[(size_t)t * 32768 + (size_t)b * 512 + j0 + ejj] = f2b(sigf(go) * tanhfast(c1));
    }

    __threadfence();      // flush h writes to device scope (wbl2)
    __syncthreads();      // all threads' writes done; also guards gate_lds WAR
    if(tid == 0)
      __hip_atomic_store(myflag, (unsigned)(t + 1),
                         __ATOMIC_RELEASE, __HIP_MEMORY_SCOPE_AGENT);
  }
}

// ---------------- emission logits via MFMA ----------------
// em[s][b][n] = [h_f(s) | h_b(s)] . fc_w[n] + fc_b[n]
// grid = 128 WGs x 256; wave handles s = wg*4 + wid (all 64 b, all 32 n), K=1024.
__global__ __launch_bounds__(256) void em_kernel(
    const unsigned short* __restrict__ st_f, const unsigned short* __restrict__ st_b,
    const unsigned short* __restrict__ fcwN, const float* __restrict__ fc_b,
    float* __restrict__ em)
{
  __shared__ __align__(16) unsigned short wlds[32 * 1024];   // 64KB, XOR-swizzled
  const int tid = threadIdx.x, wid = tid >> 6, lane = tid & 63;

  // stage fc weights, swizzle 8-elem granules by row
#pragma unroll
  for(int i = 0; i < 16; i++){
    int vid = tid + i * 256;          // 4096 vectors of 8 bf16
    int row = vid >> 7;               // 128 vectors per 1024-elem row
    int col8 = vid & 127;
    short8 v = *(const short8*)(fcwN + (size_t)row * 1024 + col8 * 8);
    int elem = row * 1024 + ((col8 * 8) ^ ((row & 7) << 3));
    *(short8*)&wlds[elem] = v;
  }
  __syncthreads();

  const int s  = blockIdx.x * 4 + wid;
  const int r0 = lane & 15, kb = (lane >> 4) * 8;
  const unsigned short* basef = st_f + (size_t)s * 32768;
  const unsigned short* baseb = st_b + (size_t)(511 - s) * 32768;

  f32x4 acc[4][2];
#pragma unroll
  for(int m = 0; m < 4; m++){ acc[m][0] = (f32x4){0,0,0,0}; acc[m][1] = (f32x4){0,0,0,0}; }

#pragma unroll
  for(int kc = 0; kc < 32; kc++){
    const unsigned short* ab = (kc < 16) ? (basef + kc * 32 + kb)
                                         : (baseb + (kc - 16) * 32 + kb);
    int koff = (kc & 15) * 32 + kb;   // same within both halves? no — use full k index
    int kfull = kc * 32 + kb;
    short8 b0 = *(const short8*)&wlds[(r0     ) * 1024 + (kfull ^ ((r0 & 7) << 3))];
    short8 b1 = *(const short8*)&wlds[(16 + r0) * 1024 + (kfull ^ ((r0 & 7) << 3))];
    (void)koff;
#pragma unroll
    for(int m = 0; m < 4; m++){
      short8 a = *(const short8*)(ab + (size_t)(m * 16 + r0) * 512);
      acc[m][0] = __builtin_amdgcn_mfma_f32_16x16x32_bf16(a, b0, acc[m][0], 0,0,0);
      acc[m][1] = __builtin_amdgcn_mfma_f32_16x16x32_bf16(a, b1, acc[m][1], 0,0,0);
    }
  }

  const float fb0 = fc_b[r0], fb1 = fc_b[16 + r0];
#pragma unroll
  for(int m = 0; m < 4; m++){
#pragma unroll
    for(int r = 0; r < 4; r++){
      int b = m * 16 + (lane >> 4) * 4 + r;
      em[((size_t)s * 64 + b) * 32 + r0]      = acc[m][0][r] + fb0;
      em[((size_t)s * 64 + b) * 32 + 16 + r0] = acc[m][1][r] + fb1;
    }
  }
}

// ---------------- CRF forward + path score, per batch element ----------------
// 1 wave per b; lanes = (i-half, j): j = lane&31, half = lane>>5 sums 16 i's.
__global__ __launch_bounds__(64) void crf_kernel(
    const float* __restrict__ em, const float* __restrict__ trans,
    const float* __restrict__ start_trans, const float* __restrict__ end_trans,
    const int* __restrict__ tags, float* __restrict__ llh)
{
  __shared__ float tr[32 * 33];
  __shared__ float al_s[32];
  __shared__ float red[64];
  const int b = blockIdx.x, lane = threadIdx.x;
  const int j = lane & 31, half = lane >> 5;

  for(int idx = lane; idx < 1024; idx += 64){
    int r = idx >> 5, cc = idx & 31;
    tr[r * 33 + cc] = trans[idx];
  }
  if(lane < 32) al_s[lane] = start_trans[lane] + em[(size_t)b * 32 + lane];
  __syncthreads();

  for(int s = 1; s < 512; s++){
    float et = em[((size_t)s * 64 + b) * 32 + j];
    float v[16];
    float m = -1e30f;
#pragma unroll
    for(int q = 0; q < 16; q++){
      int i = half * 16 + q;
      v[q] = al_s[i] + tr[i * 33 + j];
      m = fmaxf(m, v[q]);
    }
    float sum = 0.f;
#pragma unroll
    for(int q = 0; q < 16; q++) sum += __expf(v[q] - m);
    float mo = __shfl_xor(m, 32);
    float so = __shfl_xor(sum, 32);
    float M = fmaxf(m, mo);
    sum = sum * __expf(m - M) + so * __expf(mo - M);
    float nv = M + __logf(sum) + et;
    __syncthreads();
    if(half == 0) al_s[j] = nv;
    __syncthreads();
  }

  float den = 0.f;
  if(lane == 0){
    float m = -1e30f;
    for(int t2 = 0; t2 < 32; t2++) m = fmaxf(m, al_s[t2] + end_trans[t2]);
    float sum = 0.f;
    for(int t2 = 0; t2 < 32; t2++) sum += __expf(al_s[t2] + end_trans[t2] - m);
    den = m + __logf(sum);
  }

  float acc = 0.f;
  for(int s = lane; s < 512; s += 64){
    int tg = tags[b * 512 + s];
    acc += em[((size_t)s * 64 + b) * 32 + tg];
    if(s < 511){
      int tg2 = tags[b * 512 + s + 1];
      acc += trans[tg * 32 + tg2];
    }
  }
  red[lane] = acc;
  __syncthreads();
  if(lane == 0){
    float ns = 0.f;
    for(int i = 0; i < 64; i++) ns += red[i];
    float num = start_trans[tags[b * 512]] + ns + end_trans[tags[b * 512 + 511]];
    llh[b] = num - den;
  }
}

__global__ void final_kernel(const float* __restrict__ llh, float* __restrict__ out){
  __shared__ float red[64];
  int lane = threadIdx.x;
  red[lane] = llh[lane];
  __syncthreads();
  if(lane == 0){
    float s = 0.f;
    for(int i = 0; i < 64; i++) s += red[i];
    out[0] = -s / 64.f;
  }
}

extern "C" void kernel_launch(void* const* d_in, const int* in_sizes, int n_in,
                              void* d_out, int out_size, void* d_ws, size_t ws_size,
                              hipStream_t stream)
{
  const float* emb        = (const float*)d_in[0];
  const float* w_ih_f     = (const float*)d_in[1];
  const float* w_hh_f     = (const float*)d_in[2];
  const float* b_f        = (const float*)d_in[3];
  const float* w_ih_b     = (const float*)d_in[4];
  const float* w_hh_b     = (const float*)d_in[5];
  const float* b_b        = (const float*)d_in[6];
  const float* fc_w       = (const float*)d_in[7];
  const float* fc_b       = (const float*)d_in[8];
  const float* start_tr   = (const float*)d_in[9];
  const float* end_tr     = (const float*)d_in[10];
  const float* trans      = (const float*)d_in[11];
  const int*   x          = (const int*)d_in[12];
  const int*   tags       = (const int*)d_in[13];

  char* p = (char*)d_ws;
  unsigned short* e_bf  = (unsigned short*)p; p += (size_t)512 * 64 * 256 * 2;  // 16.8 MB
  unsigned short* Wc_f  = (unsigned short*)p; p += (size_t)2048 * 768 * 2;      // 3.1 MB
  unsigned short* Wc_b  = (unsigned short*)p; p += (size_t)2048 * 768 * 2;      // 3.1 MB
  unsigned short* fcwN  = (unsigned short*)p; p += (size_t)32 * 1024 * 2;       // 64 KB
  unsigned short* st_f  = (unsigned short*)p; p += (size_t)512 * 32768 * 2;     // 33.6 MB
  unsigned short* st_b  = (unsigned short*)p; p += (size_t)512 * 32768 * 2;     // 33.6 MB
  float*          em    = (float*)p;          p += (size_t)512 * 64 * 32 * 4;   // 4.2 MB
  float*          llh   = (float*)p;          p += 256;
  unsigned int*   flags = (unsigned int*)p;   p += 2 * 64 * 4 * 4;              // 2 KB

  hipLaunchKernelGGL(prep_wc_kernel, dim3(6144), dim3(256), 0, stream, w_ih_f, w_hh_f, Wc_f);
  hipLaunchKernelGGL(prep_wc_kernel, dim3(6144), dim3(256), 0, stream, w_ih_b, w_hh_b, Wc_b);
  hipLaunchKernelGGL(prep_fcw_kernel, dim3(128), dim3(256), 0, stream, fc_w, fcwN);
  hipLaunchKernelGGL(gather_kernel, dim3(32768), dim3(256), 0, stream, emb, x, e_bf);
  hipLaunchKernelGGL(init_flags_kernel, dim3(2), dim3(256), 0, stream, flags);

  hipLaunchKernelGGL(lstm_persist, dim3(128), dim3(256), 0, stream,
                     e_bf, Wc_f, Wc_b, b_f, b_b, st_f, st_b, flags);

  hipLaunchKernelGGL(em_kernel, dim3(128), dim3(256), 0, stream, st_f, st_b, fcwN, fc_b, em);
  hipLaunchKernelGGL(crf_kernel, dim3(64), dim3(64), 0, stream, em, trans, start_tr, end_tr, tags, llh);
  hipLaunchKernelGGL(final_kernel, dim3(1), dim3(64), 0, stream, llh, (float*)d_out);
}

// Round 3
// 6185.658 us; speedup vs baseline: 1.8901x; 1.8901x over previous
//
#include <hip/hip_runtime.h>
#include <hip/hip_bf16.h>
#include <cstdint>
#include <cstddef>

// Problem: V=50000 T=32 E=256 H=512 B=64 S=512
// Recurrence GEMM per dir per step: [64 x 768] @ [768 x 2048]
// 64 WGs per dir, each owns 8 h-dims (= 32 gate-cols i,f,g,o x 8).

typedef __attribute__((ext_vector_type(8))) short short8;
typedef __attribute__((ext_vector_type(4))) float f32x4;

__device__ __forceinline__ unsigned short f2b(float x){
  unsigned u = __float_as_uint(x);
  unsigned r = u + 0x7FFFu + ((u >> 16) & 1u);   // RNE
  return (unsigned short)(r >> 16);
}
__device__ __forceinline__ float b2f(unsigned short b){
  return __uint_as_float(((unsigned)b) << 16);
}
__device__ __forceinline__ float sigf(float x){
  return 1.f / (1.f + __expf(-x));
}
__device__ __forceinline__ float tanhfast(float x){
  return 1.f - 2.f / (__expf(2.f * x) + 1.f);
}

// ---------------- prep kernels ----------------

// Wc (2048 x 768) bf16 : rows gate-major (g*512 + j), cols = [w_ih | w_hh]
__global__ void prep_wc_kernel(const float* __restrict__ w_ih, const float* __restrict__ w_hh,
                               unsigned short* __restrict__ wc){
  int idx = blockIdx.x * 256 + threadIdx.x;
  if(idx >= 2048 * 768) return;
  int g = idx / 768, k = idx - g * 768;
  float v = (k < 256) ? w_ih[g * 256 + k] : w_hh[g * 512 + (k - 256)];
  wc[idx] = f2b(v);
}

// fcwN [n][k] (32 x 1024) bf16
__global__ void prep_fcw_kernel(const float* __restrict__ fc_w, unsigned short* __restrict__ fcwN){
  int idx = blockIdx.x * 256 + threadIdx.x;   // 32768
  fcwN[idx] = f2b(fc_w[idx]);
}

// gather embeddings -> bf16 (S, B, E)
__global__ void gather_kernel(const float* __restrict__ emb, const int* __restrict__ x,
                              unsigned short* __restrict__ e_bf){
  int tok = blockIdx.x;            // s*64 + b
  int s = tok >> 6, b = tok & 63;
  int row = x[b * 512 + s];
  int k = threadIdx.x;
  e_bf[(size_t)tok * 256 + k] = f2b(emb[(size_t)row * 256 + k]);
}

// zero the per-(dir,t) completion counters
__global__ void init_cnt_kernel(unsigned int* __restrict__ cnt){
  int idx = blockIdx.x * 256 + threadIdx.x;
  if(idx < 1024) cnt[idx] = 0;
}

// ---------------- persistent bidirectional LSTM ----------------
// grid = 128 WGs x 256 threads. dir = wg>>6, slice = wg&63 (8 h-dims = 32 gate-cols).
// 4 waves: mh = wid>>1 (batch half, 32 rows), nh = wid&1 (16 of the 32 gate-cols).
// Weights: 24 x short8 = 96 VGPR per lane, loaded once; c-state in registers.
// h exchange: relaxed AGENT atomics (sc1 per-line coherence, NO buffer_inv/wbl2).
// Completion: one relaxed agent atomicAdd per WG per step on cnt[dir][t], after
// a hand-rolled release (s_waitcnt vmcnt(0) following the sc1 h-stores).
__global__ __launch_bounds__(256, 1) void lstm_persist(
    const unsigned short* __restrict__ e_bf,
    const unsigned short* __restrict__ Wc_f, const unsigned short* __restrict__ Wc_b,
    const float* __restrict__ b_f, const float* __restrict__ b_b,
    unsigned short* __restrict__ st_f, unsigned short* __restrict__ st_b,
    unsigned int* __restrict__ cnt)
{
  __shared__ float gate_lds[64 * 34];   // 64 b x 32 cols, pad 34 (8B-aligned rows)

  const int tid  = threadIdx.x;
  const int wid  = tid >> 6;
  const int lane = tid & 63;
  const int dir  = blockIdx.x >> 6;
  const int slice= blockIdx.x & 63;
  const int j0   = slice * 8;

  const int mh = wid >> 1;        // batch half
  const int nh = wid & 1;         // col half
  const int r0 = lane & 15;
  const int kb = (lane >> 4) * 8;

  const unsigned short* Wc   = dir ? Wc_b : Wc_f;
  const float*          bias = dir ? b_b  : b_f;
  unsigned short*       st   = dir ? st_b : st_f;
  unsigned int*         cbase= cnt + dir * 512;

  // --- static B fragments: col c = nh*16 + r0 ; W row = (c>>3)*512 + j0 + (c&7)
  const int c = nh * 16 + r0;
  const unsigned short* wrow = Wc + (size_t)((c >> 3) * 512 + j0 + (c & 7)) * 768;
  short8 bfrag[24];
#pragma unroll
  for(int kc = 0; kc < 24; kc++)
    bfrag[kc] = *(const short8*)(wrow + kc * 32 + kb);

  // --- epilogue mapping: thread (eb = tid>>2, jp = tid&3) owns dims jj = 2jp, 2jp+1 of batch eb
  const int eb = tid >> 2, jp = tid & 3;
  const float bi0 = bias[0 * 512 + j0 + 2 * jp], bi1 = bias[0 * 512 + j0 + 2 * jp + 1];
  const float bf0 = bias[1 * 512 + j0 + 2 * jp], bf1 = bias[1 * 512 + j0 + 2 * jp + 1];
  const float bg0 = bias[2 * 512 + j0 + 2 * jp], bg1 = bias[2 * 512 + j0 + 2 * jp + 1];
  const float bo0 = bias[3 * 512 + j0 + 2 * jp], bo1 = bias[3 * 512 + j0 + 2 * jp + 1];
  float cc0 = 0.f, cc1 = 0.f;

  unsigned int* st32 = (unsigned int*)st;
  const unsigned long long* stq = (const unsigned long long*)st;
  const int arow0 = mh * 32 + r0;        // A rows for m-tile 0
  const int arow1 = arow0 + 16;          // m-tile 1

  union U { unsigned long long q[2]; short8 v; };

  for(int t = 0; t < 512; t++){
    const int t_e = dir ? (511 - t) : t;

    // ---- e-part loads + MFMAs (independent of h; runs before/while producers finish)
    const unsigned short* ep0 = e_bf + (size_t)t_e * 16384 + (size_t)arow0 * 256;
    const unsigned short* ep1 = e_bf + (size_t)t_e * 16384 + (size_t)arow1 * 256;
    short8 ef0[8], ef1[8];
#pragma unroll
    for(int kc = 0; kc < 8; kc++){
      ef0[kc] = *(const short8*)(ep0 + kc * 32 + kb);
      ef1[kc] = *(const short8*)(ep1 + kc * 32 + kb);
    }
    f32x4 aE0 = {0,0,0,0}, aO0 = {0,0,0,0};   // m-tile 0 even/odd chains
    f32x4 aE1 = {0,0,0,0}, aO1 = {0,0,0,0};   // m-tile 1
#pragma unroll
    for(int kc = 0; kc < 8; kc += 2){
      aE0 = __builtin_amdgcn_mfma_f32_16x16x32_bf16(ef0[kc],   bfrag[kc],   aE0, 0,0,0);
      aE1 = __builtin_amdgcn_mfma_f32_16x16x32_bf16(ef1[kc],   bfrag[kc],   aE1, 0,0,0);
      aO0 = __builtin_amdgcn_mfma_f32_16x16x32_bf16(ef0[kc+1], bfrag[kc+1], aO0, 0,0,0);
      aO1 = __builtin_amdgcn_mfma_f32_16x16x32_bf16(ef1[kc+1], bfrag[kc+1], aO1, 0,0,0);
    }

    if(t > 0){
      // ---- wait for all 64 producers of step t-1 (single counter, relaxed poll)
      const unsigned int* cp = cbase + (t - 1);
      int ok;
      do{
        unsigned v = __hip_atomic_load(cp, __ATOMIC_RELAXED, __HIP_MEMORY_SCOPE_AGENT);
        ok = __syncthreads_and((int)(v >= 64u));
      }while(!ok);
      asm volatile("" ::: "memory");

      // ---- h loads (sc1 relaxed agent atomics, read from coherence point)
      const unsigned long long* hq0 = stq + ((size_t)(t - 1) * 8192 + (size_t)arow0 * 128 + (lane >> 4) * 2);
      const unsigned long long* hq1 = stq + ((size_t)(t - 1) * 8192 + (size_t)arow1 * 128 + (lane >> 4) * 2);
      U h0[16], h1[16];
#pragma unroll
      for(int kc = 0; kc < 16; kc++){
        h0[kc].q[0] = __hip_atomic_load(hq0 + kc * 8,     __ATOMIC_RELAXED, __HIP_MEMORY_SCOPE_AGENT);
        h0[kc].q[1] = __hip_atomic_load(hq0 + kc * 8 + 1, __ATOMIC_RELAXED, __HIP_MEMORY_SCOPE_AGENT);
      }
#pragma unroll
      for(int kc = 0; kc < 16; kc++){
        h1[kc].q[0] = __hip_atomic_load(hq1 + kc * 8,     __ATOMIC_RELAXED, __HIP_MEMORY_SCOPE_AGENT);
        h1[kc].q[1] = __hip_atomic_load(hq1 + kc * 8 + 1, __ATOMIC_RELAXED, __HIP_MEMORY_SCOPE_AGENT);
      }
#pragma unroll
      for(int kc = 0; kc < 16; kc += 2){
        aE0 = __builtin_amdgcn_mfma_f32_16x16x32_bf16(h0[kc].v,   bfrag[8+kc], aE0, 0,0,0);
        aE1 = __builtin_amdgcn_mfma_f32_16x16x32_bf16(h1[kc].v,   bfrag[8+kc], aE1, 0,0,0);
        aO0 = __builtin_amdgcn_mfma_f32_16x16x32_bf16(h0[kc+1].v, bfrag[9+kc], aO0, 0,0,0);
        aO1 = __builtin_amdgcn_mfma_f32_16x16x32_bf16(h1[kc+1].v, bfrag[9+kc], aO1, 0,0,0);
      }
    }

    f32x4 g0 = aE0 + aO0;     // rows mh*32 + (lane>>4)*4 + r, col c
    f32x4 g1 = aE1 + aO1;     // rows +16
#pragma unroll
    for(int r = 0; r < 4; r++){
      int row = mh * 32 + (lane >> 4) * 4 + r;
      gate_lds[row * 34 + c]        = g0[r];
      gate_lds[(row + 16) * 34 + c] = g1[r];
    }
    __syncthreads();

    // ---- c/h update: thread (eb, jp), dims jj=2jp, 2jp+1
    {
      float gi0 = gate_lds[eb * 34 + 0  + 2 * jp] + bi0, gi1 = gate_lds[eb * 34 + 1  + 2 * jp] + bi1;
      float gf0_ = gate_lds[eb * 34 + 8  + 2 * jp] + bf0, gf1_ = gate_lds[eb * 34 + 9  + 2 * jp] + bf1;
      float gg0 = gate_lds[eb * 34 + 16 + 2 * jp] + bg0, gg1 = gate_lds[eb * 34 + 17 + 2 * jp] + bg1;
      float go0 = gate_lds[eb * 34 + 24 + 2 * jp] + bo0, go1 = gate_lds[eb * 34 + 25 + 2 * jp] + bo1;
      cc0 = sigf(gf0_) * cc0 + sigf(gi0) * tanhfast(gg0);
      cc1 = sigf(gf1_) * cc1 + sigf(gi1) * tanhfast(gg1);
      float h0v = sigf(go0) * tanhfast(cc0);
      float h1v = sigf(go1) * tanhfast(cc1);
      unsigned pack = (unsigned)f2b(h0v) | ((unsigned)f2b(h1v) << 16);
      __hip_atomic_store(st32 + (size_t)t * 16384 + eb * 256 + (j0 >> 1) + jp, pack,
                         __ATOMIC_RELAXED, __HIP_MEMORY_SCOPE_AGENT);
    }
    // hand-rolled release: my sc1 store acked at coherence point
    asm volatile("s_waitcnt vmcnt(0)" ::: "memory");
    __syncthreads();          // all 256 threads' stores acked (each waited its own)
    if(tid == 0)
      __hip_atomic_fetch_add(cbase + t, 1u, __ATOMIC_RELAXED, __HIP_MEMORY_SCOPE_AGENT);
  }
}

// ---------------- emission logits via MFMA ----------------
__global__ __launch_bounds__(256) void em_kernel(
    const unsigned short* __restrict__ st_f, const unsigned short* __restrict__ st_b,
    const unsigned short* __restrict__ fcwN, const float* __restrict__ fc_b,
    float* __restrict__ em)
{
  __shared__ __align__(16) unsigned short wlds[32 * 1024];   // 64KB, XOR-swizzled
  const int tid = threadIdx.x, wid = tid >> 6, lane = tid & 63;

#pragma unroll
  for(int i = 0; i < 16; i++){
    int vid = tid + i * 256;
    int row = vid >> 7;
    int col8 = vid & 127;
    short8 v = *(const short8*)(fcwN + (size_t)row * 1024 + col8 * 8);
    int elem = row * 1024 + ((col8 * 8) ^ ((row & 7) << 3));
    *(short8*)&wlds[elem] = v;
  }
  __syncthreads();

  const int s  = blockIdx.x * 4 + wid;
  const int r0 = lane & 15, kb = (lane >> 4) * 8;
  const unsigned short* basef = st_f + (size_t)s * 32768;
  const unsigned short* baseb = st_b + (size_t)(511 - s) * 32768;

  f32x4 acc[4][2];
#pragma unroll
  for(int m = 0; m < 4; m++){ acc[m][0] = (f32x4){0,0,0,0}; acc[m][1] = (f32x4){0,0,0,0}; }

#pragma unroll
  for(int kc = 0; kc < 32; kc++){
    const unsigned short* ab = (kc < 16) ? (basef + kc * 32 + kb)
                                         : (baseb + (kc - 16) * 32 + kb);
    int kfull = kc * 32 + kb;
    short8 b0 = *(const short8*)&wlds[(r0     ) * 1024 + (kfull ^ ((r0 & 7) << 3))];
    short8 b1 = *(const short8*)&wlds[(16 + r0) * 1024 + (kfull ^ ((r0 & 7) << 3))];
#pragma unroll
    for(int m = 0; m < 4; m++){
      short8 a = *(const short8*)(ab + (size_t)(m * 16 + r0) * 512);
      acc[m][0] = __builtin_amdgcn_mfma_f32_16x16x32_bf16(a, b0, acc[m][0], 0,0,0);
      acc[m][1] = __builtin_amdgcn_mfma_f32_16x16x32_bf16(a, b1, acc[m][1], 0,0,0);
    }
  }

  const float fb0 = fc_b[r0], fb1 = fc_b[16 + r0];
#pragma unroll
  for(int m = 0; m < 4; m++){
#pragma unroll
    for(int r = 0; r < 4; r++){
      int b = m * 16 + (lane >> 4) * 4 + r;
      em[((size_t)s * 64 + b) * 32 + r0]      = acc[m][0][r] + fb0;
      em[((size_t)s * 64 + b) * 32 + 16 + r0] = acc[m][1][r] + fb1;
    }
  }
}

// ---------------- CRF forward + path score, per batch element ----------------
__global__ __launch_bounds__(64) void crf_kernel(
    const float* __restrict__ em, const float* __restrict__ trans,
    const float* __restrict__ start_trans, const float* __restrict__ end_trans,
    const int* __restrict__ tags, float* __restrict__ llh)
{
  __shared__ float tr[32 * 33];
  __shared__ float al_s[32];
  __shared__ float red[64];
  const int b = blockIdx.x, lane = threadIdx.x;
  const int j = lane & 31, half = lane >> 5;

  for(int idx = lane; idx < 1024; idx += 64){
    int r = idx >> 5, cc = idx & 31;
    tr[r * 33 + cc] = trans[idx];
  }
  if(lane < 32) al_s[lane] = start_trans[lane] + em[(size_t)b * 32 + lane];
  __syncthreads();

  float et_next = em[((size_t)1 * 64 + b) * 32 + j];
  for(int s = 1; s < 512; s++){
    float et = et_next;
    if(s < 511) et_next = em[((size_t)(s + 1) * 64 + b) * 32 + j];   // prefetch
    float v[16];
    float m = -1e30f;
#pragma unroll
    for(int q = 0; q < 16; q++){
      int i = half * 16 + q;
      v[q] = al_s[i] + tr[i * 33 + j];
      m = fmaxf(m, v[q]);
    }
    float sum = 0.f;
#pragma unroll
    for(int q = 0; q < 16; q++) sum += __expf(v[q] - m);
    float mo = __shfl_xor(m, 32);
    float so = __shfl_xor(sum, 32);
    float M = fmaxf(m, mo);
    sum = sum * __expf(m - M) + so * __expf(mo - M);
    float nv = M + __logf(sum) + et;
    __syncthreads();
    if(half == 0) al_s[j] = nv;
    __syncthreads();
  }

  float den = 0.f;
  if(lane == 0){
    float m = -1e30f;
    for(int t2 = 0; t2 < 32; t2++) m = fmaxf(m, al_s[t2] + end_trans[t2]);
    float sum = 0.f;
    for(int t2 = 0; t2 < 32; t2++) sum += __expf(al_s[t2] + end_trans[t2] - m);
    den = m + __logf(sum);
  }

  float acc = 0.f;
  for(int s = lane; s < 512; s += 64){
    int tg = tags[b * 512 + s];
    acc += em[((size_t)s * 64 + b) * 32 + tg];
    if(s < 511){
      int tg2 = tags[b * 512 + s + 1];
      acc += trans[tg * 32 + tg2];
    }
  }
  red[lane] = acc;
  __syncthreads();
  if(lane == 0){
    float ns = 0.f;
    for(int i = 0; i < 64; i++) ns += red[i];
    float num = start_trans[tags[b * 512]] + ns + end_trans[tags[b * 512 + 511]];
    llh[b] = num - den;
  }
}

__global__ void final_kernel(const float* __restrict__ llh, float* __restrict__ out){
  __shared__ float red[64];
  int lane = threadIdx.x;
  red[lane] = llh[lane];
  __syncthreads();
  if(lane == 0){
    float s = 0.f;
    for(int i = 0; i < 64; i++) s += red[i];
    out[0] = -s / 64.f;
  }
}

extern "C" void kernel_launch(void* const* d_in, const int* in_sizes, int n_in,
                              void* d_out, int out_size, void* d_ws, size_t ws_size,
                              hipStream_t stream)
{
  const float* emb        = (const float*)d_in[0];
  const float* w_ih_f     = (const float*)d_in[1];
  const float* w_hh_f     = (const float*)d_in[2];
  const float* b_f        = (const float*)d_in[3];
  const float* w_ih_b     = (const float*)d_in[4];
  const float* w_hh_b     = (const float*)d_in[5];
  const float* b_b        = (const float*)d_in[6];
  const float* fc_w       = (const float*)d_in[7];
  const float* fc_b       = (const float*)d_in[8];
  const float* start_tr   = (const float*)d_in[9];
  const float* end_tr     = (const float*)d_in[10];
  const float* trans      = (const float*)d_in[11];
  const int*   x          = (const int*)d_in[12];
  const int*   tags       = (const int*)d_in[13];

  char* p = (char*)d_ws;
  unsigned short* e_bf  = (unsigned short*)p; p += (size_t)512 * 64 * 256 * 2;  // 16.8 MB
  unsigned short* Wc_f  = (unsigned short*)p; p += (size_t)2048 * 768 * 2;      // 3.1 MB
  unsigned short* Wc_b  = (unsigned short*)p; p += (size_t)2048 * 768 * 2;      // 3.1 MB
  unsigned short* fcwN  = (unsigned short*)p; p += (size_t)32 * 1024 * 2;       // 64 KB
  unsigned short* st_f  = (unsigned short*)p; p += (size_t)512 * 32768 * 2;     // 33.6 MB
  unsigned short* st_b  = (unsigned short*)p; p += (size_t)512 * 32768 * 2;     // 33.6 MB
  float*          em    = (float*)p;          p += (size_t)512 * 64 * 32 * 4;   // 4.2 MB
  float*          llh   = (float*)p;          p += 256;
  unsigned int*   cnt   = (unsigned int*)p;   p += 1024 * 4;                    // 4 KB

  hipLaunchKernelGGL(prep_wc_kernel, dim3(6144), dim3(256), 0, stream, w_ih_f, w_hh_f, Wc_f);
  hipLaunchKernelGGL(prep_wc_kernel, dim3(6144), dim3(256), 0, stream, w_ih_b, w_hh_b, Wc_b);
  hipLaunchKernelGGL(prep_fcw_kernel, dim3(128), dim3(256), 0, stream, fc_w, fcwN);
  hipLaunchKernelGGL(gather_kernel, dim3(32768), dim3(256), 0, stream, emb, x, e_bf);
  hipLaunchKernelGGL(init_cnt_kernel, dim3(4), dim3(256), 0, stream, cnt);

  hipLaunchKernelGGL(lstm_persist, dim3(128), dim3(256), 0, stream,
                     e_bf, Wc_f, Wc_b, b_f, b_b, st_f, st_b, cnt);

  hipLaunchKernelGGL(em_kernel, dim3(128), dim3(256), 0, stream, st_f, st_b, fcwN, fc_b, em);
  hipLaunchKernelGGL(crf_kernel, dim3(64), dim3(64), 0, stream, em, trans, start_tr, end_tr, tags, llh);
  hipLaunchKernelGGL(final_kernel, dim3(1), dim3(64), 0, stream, llh, (float*)d_out);
}